// Round 3
// baseline (253.026 us; speedup 1.0000x reference)
//
#include <hip/hip_runtime.h>

// out = relu(w[0]*t1 + w[1]*t2 + b[0])  -- elementwise fp32, n = 25,690,112.
// 4x unrolled block-stride float4 batches (8 loads in flight per thread
// before any waitcnt) + non-temporal stores so the output stream doesn't
// evict the L3-resident inputs. Native clang vector type so
// __builtin_nontemporal_store accepts it.

typedef float v4f __attribute__((ext_vector_type(4)));

__global__ void __launch_bounds__(256) fused_merge_relu_f4x4(
    const v4f* __restrict__ t1,
    const v4f* __restrict__ t2,
    v4f* __restrict__ out,
    const float* __restrict__ w,
    const float* __restrict__ b,
    int n4)
{
    const float w0 = w[0];
    const float w1 = w[1];
    const float bb = b[0];

    const int base = blockIdx.x * 1024 + threadIdx.x;  // 256 threads * 4 batches

    if (base + 768 < n4) {
        // Fast path: issue all 8 independent coalesced 16B loads up front.
        v4f a0 = t1[base];
        v4f a1 = t1[base + 256];
        v4f a2 = t1[base + 512];
        v4f a3 = t1[base + 768];
        v4f c0 = t2[base];
        v4f c1 = t2[base + 256];
        v4f c2 = t2[base + 512];
        v4f c3 = t2[base + 768];

        v4f r0, r1, r2, r3;
        #pragma unroll
        for (int k = 0; k < 4; ++k) {
            r0[k] = fmaxf(fmaf(w0, a0[k], fmaf(w1, c0[k], bb)), 0.0f);
            r1[k] = fmaxf(fmaf(w0, a1[k], fmaf(w1, c1[k], bb)), 0.0f);
            r2[k] = fmaxf(fmaf(w0, a2[k], fmaf(w1, c2[k], bb)), 0.0f);
            r3[k] = fmaxf(fmaf(w0, a3[k], fmaf(w1, c3[k], bb)), 0.0f);
        }

        __builtin_nontemporal_store(r0, &out[base]);
        __builtin_nontemporal_store(r1, &out[base + 256]);
        __builtin_nontemporal_store(r2, &out[base + 512]);
        __builtin_nontemporal_store(r3, &out[base + 768]);
    } else {
        // Tail path (last block only).
        for (int j = 0; j < 4; ++j) {
            int i = base + j * 256;
            if (i < n4) {
                v4f a = t1[i];
                v4f c = t2[i];
                v4f r;
                #pragma unroll
                for (int k = 0; k < 4; ++k)
                    r[k] = fmaxf(fmaf(w0, a[k], fmaf(w1, c[k], bb)), 0.0f);
                __builtin_nontemporal_store(r, &out[i]);
            }
        }
    }
}

__global__ void __launch_bounds__(256) fused_merge_relu_tail(
    const float* __restrict__ t1,
    const float* __restrict__ t2,
    float* __restrict__ out,
    const float* __restrict__ w,
    const float* __restrict__ b,
    int start, int n)
{
    int i = start + blockIdx.x * blockDim.x + threadIdx.x;
    if (i < n) {
        out[i] = fmaxf(fmaf(w[0], t1[i], fmaf(w[1], t2[i], b[0])), 0.0f);
    }
}

extern "C" void kernel_launch(void* const* d_in, const int* in_sizes, int n_in,
                              void* d_out, int out_size, void* d_ws, size_t ws_size,
                              hipStream_t stream) {
    const float* t1 = (const float*)d_in[0];
    const float* t2 = (const float*)d_in[1];
    const float* w  = (const float*)d_in[2];
    const float* b  = (const float*)d_in[3];
    float* out = (float*)d_out;

    const int n  = out_size;          // 25,690,112
    const int n4 = n / 4;             // 6,422,528 float4 elements
    const int tail = n - n4 * 4;      // 0 for this shape

    const int block = 256;
    const int per_block = block * 4;  // 1024 float4 per block
    int grid = (n4 + per_block - 1) / per_block;   // 6272, exact cover

    fused_merge_relu_f4x4<<<grid, block, 0, stream>>>(
        (const v4f*)t1, (const v4f*)t2, (v4f*)out, w, b, n4);

    if (tail > 0) {
        int tg = (tail + block - 1) / block;
        fused_merge_relu_tail<<<tg, block, 0, stream>>>(t1, t2, out, w, b, n4 * 4, n);
    }
}

// Round 6
// 236.807 us; speedup vs baseline: 1.0685x; 1.0685x over previous
//
#include <hip/hip_runtime.h>

// out = relu(w[0]*t1 + w[1]*t2 + b[0])  -- elementwise fp32, n = 25,690,112.
// Round 5 (rebench; round-5 run hit GPUAcquisitionTimeout): coherent nt hints
// on ALL streams (evict-first, no bypass -- the asm sc0/sc1 bypass broke
// validation via stale cached poison) + bijective XCD-chunked block mapping
// (6272 = 8 x 784 contiguous chunks per XCD).

typedef float v4f __attribute__((ext_vector_type(4)));

__global__ void __launch_bounds__(256) fused_merge_relu_f4x4(
    const v4f* __restrict__ t1,
    const v4f* __restrict__ t2,
    v4f* __restrict__ out,
    const float* __restrict__ w,
    const float* __restrict__ b,
    int n4)
{
    const float w0 = w[0];
    const float w1 = w[1];
    const float bb = b[0];

    // Bijective XCD swizzle: hardware round-robins blockIdx across 8 XCDs;
    // remap so each XCD owns a contiguous 784-block span of the buffers.
    const int per_xcd = gridDim.x >> 3;    // 784
    const int swz = (blockIdx.x & 7) * per_xcd + (blockIdx.x >> 3);

    const int base = swz * 1024 + threadIdx.x;  // 256 threads * 4 batches

    if (base + 768 < n4) {
        // 8 independent coalesced 16B nt loads in flight before any waitcnt.
        v4f a0 = __builtin_nontemporal_load(&t1[base]);
        v4f a1 = __builtin_nontemporal_load(&t1[base + 256]);
        v4f a2 = __builtin_nontemporal_load(&t1[base + 512]);
        v4f a3 = __builtin_nontemporal_load(&t1[base + 768]);
        v4f c0 = __builtin_nontemporal_load(&t2[base]);
        v4f c1 = __builtin_nontemporal_load(&t2[base + 256]);
        v4f c2 = __builtin_nontemporal_load(&t2[base + 512]);
        v4f c3 = __builtin_nontemporal_load(&t2[base + 768]);

        v4f r0, r1, r2, r3;
        #pragma unroll
        for (int k = 0; k < 4; ++k) {
            r0[k] = fmaxf(fmaf(w0, a0[k], fmaf(w1, c0[k], bb)), 0.0f);
            r1[k] = fmaxf(fmaf(w0, a1[k], fmaf(w1, c1[k], bb)), 0.0f);
            r2[k] = fmaxf(fmaf(w0, a2[k], fmaf(w1, c2[k], bb)), 0.0f);
            r3[k] = fmaxf(fmaf(w0, a3[k], fmaf(w1, c3[k], bb)), 0.0f);
        }

        __builtin_nontemporal_store(r0, &out[base]);
        __builtin_nontemporal_store(r1, &out[base + 256]);
        __builtin_nontemporal_store(r2, &out[base + 512]);
        __builtin_nontemporal_store(r3, &out[base + 768]);
    } else {
        for (int j = 0; j < 4; ++j) {
            int i = base + j * 256;
            if (i < n4) {
                v4f a = __builtin_nontemporal_load(&t1[i]);
                v4f c = __builtin_nontemporal_load(&t2[i]);
                v4f r;
                #pragma unroll
                for (int k = 0; k < 4; ++k)
                    r[k] = fmaxf(fmaf(w0, a[k], fmaf(w1, c[k], bb)), 0.0f);
                __builtin_nontemporal_store(r, &out[i]);
            }
        }
    }
}

__global__ void __launch_bounds__(256) fused_merge_relu_tail(
    const float* __restrict__ t1,
    const float* __restrict__ t2,
    float* __restrict__ out,
    const float* __restrict__ w,
    const float* __restrict__ b,
    int start, int n)
{
    int i = start + blockIdx.x * blockDim.x + threadIdx.x;
    if (i < n) {
        out[i] = fmaxf(fmaf(w[0], t1[i], fmaf(w[1], t2[i], b[0])), 0.0f);
    }
}

extern "C" void kernel_launch(void* const* d_in, const int* in_sizes, int n_in,
                              void* d_out, int out_size, void* d_ws, size_t ws_size,
                              hipStream_t stream) {
    const float* t1 = (const float*)d_in[0];
    const float* t2 = (const float*)d_in[1];
    const float* w  = (const float*)d_in[2];
    const float* b  = (const float*)d_in[3];
    float* out = (float*)d_out;

    const int n  = out_size;          // 25,690,112
    const int n4 = n / 4;             // 6,422,528 float4 = 6272 * 1024 exactly
    const int tail = n - n4 * 4;      // 0 for this shape

    const int block = 256;
    const int per_block = block * 4;  // 1024 float4 per block
    int grid = (n4 + per_block - 1) / per_block;   // 6272 = 8 * 784

    fused_merge_relu_f4x4<<<grid, block, 0, stream>>>(
        (const v4f*)t1, (const v4f*)t2, (v4f*)out, w, b, n4);

    if (tail > 0) {
        int tg = (tail + block - 1) / block;
        fused_merge_relu_tail<<<tg, block, 0, stream>>>(t1, t2, out, w, b, n4 * 4, n);
    }
}